// Round 1
// baseline (2204.064 us; speedup 1.0000x reference)
//
#include <hip/hip_runtime.h>
#include <hip/hip_bf16.h>

// Problem constants (AdaptiveGraphWaveletConv): B=4, N=50000, F_IN=F_OUT=128, K=3, E=800000
#define BB 4
#define NN 50000
#define FF 128
#define EE 800000
#define BNF (BB * NN * FF)

// ---------------- CSR build (bucket edges by dst) ----------------

__global__ __launch_bounds__(256) void hist_kernel(const int* __restrict__ ei,
                                                   int* __restrict__ deg) {
    int e = blockIdx.x * 256 + threadIdx.x;
    if (e < EE) atomicAdd(&deg[ei[e]], 1);  // ei[0][e] = dst
}

// Single-block exclusive scan of deg[0..NN-1] -> row_ptr[0..NN]
__global__ __launch_bounds__(256) void scan_kernel(const int* __restrict__ deg,
                                                   int* __restrict__ row_ptr) {
    __shared__ int buf[256];
    __shared__ int carry_s;
    int tid = threadIdx.x;
    if (tid == 0) carry_s = 0;
    __syncthreads();
    for (int base = 0; base < NN; base += 256) {
        int i = base + tid;
        int v = (i < NN) ? deg[i] : 0;
        buf[tid] = v;
        __syncthreads();
        #pragma unroll
        for (int off = 1; off < 256; off <<= 1) {
            int t = (tid >= off) ? buf[tid - off] : 0;
            __syncthreads();
            buf[tid] += t;
            __syncthreads();
        }
        if (i < NN) row_ptr[i] = carry_s + buf[tid] - v;  // exclusive
        int tot = buf[255];
        __syncthreads();
        if (tid == 0) carry_s += tot;
        __syncthreads();
    }
    if (tid == 0) row_ptr[NN] = carry_s;
}

__global__ __launch_bounds__(256) void build_kernel(const int* __restrict__ ei,
                                                    const float* __restrict__ ea,
                                                    const int* __restrict__ row_ptr,
                                                    int* __restrict__ cursor,
                                                    int* __restrict__ cols,
                                                    float* __restrict__ wv) {
    int e = blockIdx.x * 256 + threadIdx.x;
    if (e < EE) {
        int d = ei[e];           // dst
        int s = ei[EE + e];      // src
        int pos = atomicAdd(&cursor[d], 1);
        int idx = row_ptr[d] + pos;
        cols[idx] = s;
        wv[idx] = ea[e];
    }
}

// ---------------- Message passing (gather form, no atomics) ----------------
// Tout[b,n,:] = coef * sum_{e in row(n)} w[e] * Tin[b, col[e], :]  (- Tsub[b,n,:] if given)
// One wave per (b, n); lane owns 2 consecutive features (float2).
__global__ __launch_bounds__(256) void mp_kernel(const float* __restrict__ Tin,
                                                 const float* __restrict__ Tsub,
                                                 float* __restrict__ Tout,
                                                 const int* __restrict__ row_ptr,
                                                 const int* __restrict__ cols,
                                                 const float* __restrict__ wv,
                                                 float coef) {
    int gw = (blockIdx.x * 256 + threadIdx.x) >> 6;  // global wave id = b*NN + n
    int lane = threadIdx.x & 63;
    int b = gw / NN;
    int n = gw - b * NN;
    int rs = row_ptr[n];
    int re = row_ptr[n + 1];
    const float* __restrict__ base = Tin + (size_t)b * NN * FF + (lane << 1);
    float ax = 0.f, ay = 0.f;
    for (int e = rs; e < re; ++e) {
        int c = cols[e];
        float ww = wv[e];
        const float2 v = *reinterpret_cast<const float2*>(base + (size_t)c * FF);
        ax += ww * v.x;
        ay += ww * v.y;
    }
    size_t o = (size_t)gw * FF + (lane << 1);
    float rx = coef * ax, ry = coef * ay;
    if (Tsub) {
        const float2 s = *reinterpret_cast<const float2*>(Tsub + o);
        rx -= s.x;
        ry -= s.y;
    }
    float2 r;
    r.x = rx;
    r.y = ry;
    *reinterpret_cast<float2*>(Tout + o) = r;
}

// ---------------- Dense combine: out = sum_k T_k @ Th0[k] + s * (sum_k T_k @ Th1[k]) + bias
// Block tile: 64 nodes x 128 outs. 256 threads: og = tid&31 (4 outs), ng = tid>>5 (8 nodes).
__global__ __launch_bounds__(256) void combine_kernel(const float* __restrict__ t0,
                                                      const float* __restrict__ t1,
                                                      const float* __restrict__ t2,
                                                      const float* __restrict__ t3,
                                                      const float* __restrict__ Th0,
                                                      const float* __restrict__ Th1,
                                                      const float* __restrict__ bias,
                                                      const float* __restrict__ s_local,
                                                      float* __restrict__ out) {
    __shared__ float Tt[64][129];  // +1 pad kills stride-512B bank conflicts
    int b = blockIdx.y;
    int n0 = blockIdx.x * 64;
    int tid = threadIdx.x;
    int og = tid & 31;
    int ng = tid >> 5;

    float4 acc0[8], acc1[8];
    #pragma unroll
    for (int j = 0; j < 8; ++j) {
        acc0[j] = make_float4(0.f, 0.f, 0.f, 0.f);
        acc1[j] = make_float4(0.f, 0.f, 0.f, 0.f);
    }

    const float* Ts[4] = {t0, t1, t2, t3};
    for (int k = 0; k < 4; ++k) {
        if (k) __syncthreads();
        const float* __restrict__ Tk = Ts[k] + (size_t)b * NN * FF;
        // stage 64x128 tile: 2048 float4 / 256 threads = 8 each, coalesced
        #pragma unroll
        for (int it = 0; it < 8; ++it) {
            int idx = tid + it * 256;
            int row = idx >> 5;
            int c4 = (idx & 31) << 2;
            int gn = n0 + row;
            if (gn > NN - 1) gn = NN - 1;  // clamp (reads valid, writes masked later)
            const float4 v = *reinterpret_cast<const float4*>(Tk + (size_t)gn * FF + c4);
            Tt[row][c4 + 0] = v.x;
            Tt[row][c4 + 1] = v.y;
            Tt[row][c4 + 2] = v.z;
            Tt[row][c4 + 3] = v.w;
        }
        __syncthreads();
        const float* __restrict__ p0 = Th0 + (k << 14) + (og << 2);
        const float* __restrict__ p1 = Th1 + (k << 14) + (og << 2);
        for (int f = 0; f < 128; ++f) {
            const float4 th0 = *reinterpret_cast<const float4*>(p0 + (f << 7));
            const float4 th1 = *reinterpret_cast<const float4*>(p1 + (f << 7));
            #pragma unroll
            for (int j = 0; j < 8; ++j) {
                float tv = Tt[ng * 8 + j][f];
                acc0[j].x += tv * th0.x;
                acc0[j].y += tv * th0.y;
                acc0[j].z += tv * th0.z;
                acc0[j].w += tv * th0.w;
                acc1[j].x += tv * th1.x;
                acc1[j].y += tv * th1.y;
                acc1[j].z += tv * th1.z;
                acc1[j].w += tv * th1.w;
            }
        }
    }

    const float4 bs = *reinterpret_cast<const float4*>(bias + (og << 2));
    #pragma unroll
    for (int j = 0; j < 8; ++j) {
        int n = n0 + ng * 8 + j;
        if (n < NN) {
            float sv = s_local[b * NN + n];
            float4 r;
            r.x = acc0[j].x + sv * acc1[j].x + bs.x;
            r.y = acc0[j].y + sv * acc1[j].y + bs.y;
            r.z = acc0[j].z + sv * acc1[j].z + bs.z;
            r.w = acc0[j].w + sv * acc1[j].w + bs.w;
            *reinterpret_cast<float4*>(out + ((size_t)b * NN + n) * FF + (og << 2)) = r;
        }
    }
}

// ---------------- Launch ----------------

extern "C" void kernel_launch(void* const* d_in, const int* in_sizes, int n_in,
                              void* d_out, int out_size, void* d_ws, size_t ws_size,
                              hipStream_t stream) {
    const float* x       = (const float*)d_in[0];  // [B,N,F]
    const int*   ei      = (const int*)d_in[1];    // [2,E] row0=dst row1=src
    const float* ea      = (const float*)d_in[2];  // [E]
    const float* s_local = (const float*)d_in[3];  // [B,N]
    const float* Th0     = (const float*)d_in[4];  // [K+1,F,F]
    const float* Th1     = (const float*)d_in[5];  // [K+1,F,F]
    const float* bias    = (const float*)d_in[6];  // [F]
    float* out = (float*)d_out;

    // Workspace layout (~314.2 MB)
    float* T1 = (float*)d_ws;
    float* T2 = T1 + BNF;
    float* T3 = T2 + BNF;
    int* deg     = (int*)(T3 + BNF);
    int* cursor  = deg + NN;
    int* row_ptr = cursor + NN;
    int* cols    = row_ptr + (NN + 1);
    float* wv    = (float*)(cols + EE);

    hipMemsetAsync(deg, 0, 2 * NN * sizeof(int), stream);  // deg + cursor

    hist_kernel<<<(EE + 255) / 256, 256, 0, stream>>>(ei, deg);
    scan_kernel<<<1, 256, 0, stream>>>(deg, row_ptr);
    build_kernel<<<(EE + 255) / 256, 256, 0, stream>>>(ei, ea, row_ptr, cursor, cols, wv);

    // Chebyshev: T1 = mp(x); T2 = 2*mp(T1) - x; T3 = 2*mp(T2) - T1
    const int mp_blocks = (BB * NN) / 4;  // 4 waves/block, one wave per (b,n)
    mp_kernel<<<mp_blocks, 256, 0, stream>>>(x, nullptr, T1, row_ptr, cols, wv, 1.0f);
    mp_kernel<<<mp_blocks, 256, 0, stream>>>(T1, x, T2, row_ptr, cols, wv, 2.0f);
    mp_kernel<<<mp_blocks, 256, 0, stream>>>(T2, T1, T3, row_ptr, cols, wv, 2.0f);

    dim3 g((NN + 63) / 64, BB);
    combine_kernel<<<g, 256, 0, stream>>>(x, T1, T2, T3, Th0, Th1, bias, s_local, out);
}

// Round 2
// 1624.480 us; speedup vs baseline: 1.3568x; 1.3568x over previous
//
#include <hip/hip_runtime.h>
#include <hip/hip_bf16.h>

// Problem constants: B=4, N=50000, F_IN=F_OUT=128, K=3, E=800000
#define BB 4
#define NN 50000
#define FF 128
#define EE 800000
#define BNF (BB * NN * FF)

typedef __bf16 bf16;
typedef __attribute__((ext_vector_type(8))) __bf16 bf16x8;
typedef __attribute__((ext_vector_type(4))) float f32x4;

// ---------------- CSR build (bucket edges by dst) ----------------

__global__ __launch_bounds__(256) void hist_kernel(const int* __restrict__ ei,
                                                   int* __restrict__ deg) {
    int e = blockIdx.x * 256 + threadIdx.x;
    if (e < EE) atomicAdd(&deg[ei[e]], 1);  // ei[0][e] = dst
}

__global__ __launch_bounds__(256) void scan_kernel(const int* __restrict__ deg,
                                                   int* __restrict__ row_ptr) {
    __shared__ int buf[256];
    __shared__ int carry_s;
    int tid = threadIdx.x;
    if (tid == 0) carry_s = 0;
    __syncthreads();
    for (int base = 0; base < NN; base += 256) {
        int i = base + tid;
        int v = (i < NN) ? deg[i] : 0;
        buf[tid] = v;
        __syncthreads();
        #pragma unroll
        for (int off = 1; off < 256; off <<= 1) {
            int t = (tid >= off) ? buf[tid - off] : 0;
            __syncthreads();
            buf[tid] += t;
            __syncthreads();
        }
        if (i < NN) row_ptr[i] = carry_s + buf[tid] - v;  // exclusive
        int tot = buf[255];
        __syncthreads();
        if (tid == 0) carry_s += tot;
        __syncthreads();
    }
    if (tid == 0) row_ptr[NN] = carry_s;
}

__global__ __launch_bounds__(256) void build_kernel(const int* __restrict__ ei,
                                                    const float* __restrict__ ea,
                                                    const int* __restrict__ row_ptr,
                                                    int* __restrict__ cursor,
                                                    int* __restrict__ cols,
                                                    float* __restrict__ wv) {
    int e = blockIdx.x * 256 + threadIdx.x;
    if (e < EE) {
        int d = ei[e];           // dst
        int s = ei[EE + e];      // src
        int pos = atomicAdd(&cursor[d], 1);
        int idx = row_ptr[d] + pos;
        cols[idx] = s;
        wv[idx] = ea[e];
    }
}

// ---------------- Message passing (gather form, no atomics) ----------------
__global__ __launch_bounds__(256) void mp_kernel(const float* __restrict__ Tin,
                                                 const float* __restrict__ Tsub,
                                                 float* __restrict__ Tout,
                                                 const int* __restrict__ row_ptr,
                                                 const int* __restrict__ cols,
                                                 const float* __restrict__ wv,
                                                 float coef) {
    int gw = (blockIdx.x * 256 + threadIdx.x) >> 6;  // b*NN + n
    int lane = threadIdx.x & 63;
    int b = gw / NN;
    int n = gw - b * NN;
    int rs = row_ptr[n];
    int re = row_ptr[n + 1];
    const float* __restrict__ base = Tin + (size_t)b * NN * FF + (lane << 1);
    float ax = 0.f, ay = 0.f;
    for (int e = rs; e < re; ++e) {
        int c = cols[e];
        float ww = wv[e];
        const float2 v = *reinterpret_cast<const float2*>(base + (size_t)c * FF);
        ax += ww * v.x;
        ay += ww * v.y;
    }
    size_t o = (size_t)gw * FF + (lane << 1);
    float rx = coef * ax, ry = coef * ay;
    if (Tsub) {
        const float2 s = *reinterpret_cast<const float2*>(Tsub + o);
        rx -= s.x;
        ry -= s.y;
    }
    float2 r;
    r.x = rx;
    r.y = ry;
    *reinterpret_cast<float2*>(Tout + o) = r;
}

// ---------------- W^T prep: WT[pc][kk] bf16, pc = permuted phys col ----------------
// pc -> g=pc>>6 (wave), c64=pc&63, half=c64>>5 (0:Th0 1:Th1), o = g*32 + (c64&31)
__global__ __launch_bounds__(256) void prep_wt(const float* __restrict__ Th0,
                                               const float* __restrict__ Th1,
                                               bf16* __restrict__ WT) {
    int idx = blockIdx.x * 256 + threadIdx.x;  // 256*512 total
    int r = idx >> 9;
    int kk = idx & 511;
    int g = r >> 6, c64 = r & 63, half = c64 >> 5, o = g * 32 + (c64 & 31);
    int karr = kk >> 7, f = kk & 127;
    const float* src = half ? Th1 : Th0;
    WT[idx] = (bf16)src[(karr << 14) + (f << 7) + o];
}

// ---------------- MFMA combine ----------------
// Block: 128 nodes x 256 phys cols (128 outs x {Th0,Th1}), BK=64, K=512.
// 8 waves (2M x 4N), wave tile 64x64, acc[4][4] of 16x16 frags.
// LDS rows are 128B: XOR-swizzle chunk^=(row&7) on write+read -> 2-way (free).
__global__ __launch_bounds__(512) void combine_mfma(const float* __restrict__ t0,
                                                    const float* __restrict__ t1,
                                                    const float* __restrict__ t2,
                                                    const float* __restrict__ t3,
                                                    const bf16* __restrict__ WT,
                                                    const float* __restrict__ bias,
                                                    const float* __restrict__ s_local,
                                                    float* __restrict__ out) {
    __shared__ bf16 As[128 * 64];  // 16 KB
    __shared__ bf16 Bs[256 * 64];  // 32 KB
    int b = blockIdx.y;
    int n0 = blockIdx.x * 128;
    int tid = threadIdx.x;
    int w = tid >> 6, lane = tid & 63;
    int wr = w >> 2, wc = w & 3;
    int l16 = lane & 15, lg = lane >> 4;

    const float* Aarr[4] = {t0, t1, t2, t3};

    f32x4 acc[4][4];
    #pragma unroll
    for (int mi = 0; mi < 4; ++mi)
        #pragma unroll
        for (int ni = 0; ni < 4; ++ni)
            acc[mi][ni] = (f32x4){0.f, 0.f, 0.f, 0.f};

    for (int ks = 0; ks < 8; ++ks) {
        __syncthreads();  // previous compute done before overwrite
        // ---- stage A: 128 rows x 64 f, fp32 -> bf16, swizzled ----
        {
            int karr = ks >> 1;
            int f0 = (ks & 1) * 64;
            const float* __restrict__ Ak = Aarr[karr] + (size_t)b * NN * FF;
            #pragma unroll
            for (int i = 0; i < 2; ++i) {
                int s = tid * 2 + i;
                int row = s >> 3, p = s & 7;
                int c = p ^ (row & 7);
                int gn = n0 + row;
                if (gn >= NN) gn = NN - 1;
                const float4* src = reinterpret_cast<const float4*>(Ak + (size_t)gn * FF + f0 + c * 8);
                float4 v0 = src[0];
                float4 v1 = src[1];
                bf16x8 bv;
                bv[0] = (bf16)v0.x; bv[1] = (bf16)v0.y; bv[2] = (bf16)v0.z; bv[3] = (bf16)v0.w;
                bv[4] = (bf16)v1.x; bv[5] = (bf16)v1.y; bv[6] = (bf16)v1.z; bv[7] = (bf16)v1.w;
                *reinterpret_cast<bf16x8*>(&As[s * 8]) = bv;
            }
        }
        // ---- stage B: 256 o-rows x 64 kk from WT (bf16 already), swizzled ----
        {
            #pragma unroll
            for (int i = 0; i < 4; ++i) {
                int s = tid * 4 + i;
                int orow = s >> 3, p = s & 7;
                int c = p ^ (orow & 7);
                bf16x8 bv = *reinterpret_cast<const bf16x8*>(WT + orow * 512 + ks * 64 + c * 8);
                *reinterpret_cast<bf16x8*>(&Bs[s * 8]) = bv;
            }
        }
        __syncthreads();
        // ---- fragments + MFMA ----
        #pragma unroll
        for (int ksub = 0; ksub < 2; ++ksub) {
            bf16x8 af[4], bfr[4];
            #pragma unroll
            for (int mi = 0; mi < 4; ++mi) {
                int row = wr * 64 + mi * 16 + l16;
                int cc = ksub * 4 + lg;
                int p = cc ^ (row & 7);
                af[mi] = *reinterpret_cast<const bf16x8*>(&As[row * 64 + p * 8]);
            }
            #pragma unroll
            for (int ni = 0; ni < 4; ++ni) {
                int orow = wc * 64 + ni * 16 + l16;
                int cc = ksub * 4 + lg;
                int p = cc ^ (orow & 7);
                bfr[ni] = *reinterpret_cast<const bf16x8*>(&Bs[orow * 64 + p * 8]);
            }
            #pragma unroll
            for (int mi = 0; mi < 4; ++mi)
                #pragma unroll
                for (int ni = 0; ni < 4; ++ni)
                    acc[mi][ni] = __builtin_amdgcn_mfma_f32_16x16x32_bf16(af[mi], bfr[ni], acc[mi][ni], 0, 0, 0);
        }
    }

    // ---- epilogue: out = acc0 + s*acc1 + bias (wave-local thanks to WT perm) ----
    #pragma unroll
    for (int ni = 0; ni < 2; ++ni) {
        int o = wc * 32 + ni * 16 + l16;
        float bs = bias[o];
        #pragma unroll
        for (int mi = 0; mi < 4; ++mi) {
            #pragma unroll
            for (int j = 0; j < 4; ++j) {
                int n = n0 + wr * 64 + mi * 16 + lg * 4 + j;
                if (n < NN) {
                    float sv = s_local[b * NN + n];
                    out[((size_t)b * NN + n) * FF + o] =
                        acc[mi][ni][j] + sv * acc[mi][ni + 2][j] + bs;
                }
            }
        }
    }
}

// ---------------- Launch ----------------

extern "C" void kernel_launch(void* const* d_in, const int* in_sizes, int n_in,
                              void* d_out, int out_size, void* d_ws, size_t ws_size,
                              hipStream_t stream) {
    const float* x       = (const float*)d_in[0];
    const int*   ei      = (const int*)d_in[1];
    const float* ea      = (const float*)d_in[2];
    const float* s_local = (const float*)d_in[3];
    const float* Th0     = (const float*)d_in[4];
    const float* Th1     = (const float*)d_in[5];
    const float* bias    = (const float*)d_in[6];
    float* out = (float*)d_out;

    // Workspace layout (~317 MB)
    float* T1 = (float*)d_ws;
    float* T2 = T1 + BNF;
    float* T3 = T2 + BNF;
    bf16* WT = (bf16*)(T3 + BNF);          // 256*512 bf16 = 256 KB (16B-aligned)
    int* deg     = (int*)(WT + 256 * 512);
    int* cursor  = deg + NN;
    int* row_ptr = cursor + NN;
    int* cols    = row_ptr + (NN + 1);
    float* wv    = (float*)(cols + EE);

    hipMemsetAsync(deg, 0, 2 * NN * sizeof(int), stream);  // deg + cursor

    hist_kernel<<<(EE + 255) / 256, 256, 0, stream>>>(ei, deg);
    scan_kernel<<<1, 256, 0, stream>>>(deg, row_ptr);
    build_kernel<<<(EE + 255) / 256, 256, 0, stream>>>(ei, ea, row_ptr, cursor, cols, wv);
    prep_wt<<<512, 256, 0, stream>>>(Th0, Th1, WT);

    // Chebyshev: T1 = mp(x); T2 = 2*mp(T1) - x; T3 = 2*mp(T2) - T1
    const int mp_blocks = (BB * NN) / 4;
    mp_kernel<<<mp_blocks, 256, 0, stream>>>(x, nullptr, T1, row_ptr, cols, wv, 1.0f);
    mp_kernel<<<mp_blocks, 256, 0, stream>>>(T1, x, T2, row_ptr, cols, wv, 2.0f);
    mp_kernel<<<mp_blocks, 256, 0, stream>>>(T2, T1, T3, row_ptr, cols, wv, 2.0f);

    dim3 g((NN + 127) / 128, BB);
    combine_mfma<<<g, 512, 0, stream>>>(x, T1, T2, T3, WT, bias, s_local, out);
}

// Round 3
// 1369.984 us; speedup vs baseline: 1.6088x; 1.1858x over previous
//
#include <hip/hip_runtime.h>
#include <hip/hip_bf16.h>

// Problem constants: B=4, N=50000, F_IN=F_OUT=128, K=3, E=800000
#define BB 4
#define NN 50000
#define FF 128
#define EE 800000
#define BNF (BB * NN * FF)

typedef __bf16 bf16;
typedef __attribute__((ext_vector_type(8))) __bf16 bf16x8;
typedef __attribute__((ext_vector_type(4))) float f32x4;

// ---------------- CSR build (bucket edges by dst) ----------------

__global__ __launch_bounds__(256) void hist_kernel(const int* __restrict__ ei,
                                                   int* __restrict__ deg) {
    int e = blockIdx.x * 256 + threadIdx.x;
    if (e < EE) atomicAdd(&deg[ei[e]], 1);  // ei[0][e] = dst
}

__global__ __launch_bounds__(256) void scan_kernel(const int* __restrict__ deg,
                                                   int* __restrict__ row_ptr) {
    __shared__ int buf[256];
    __shared__ int carry_s;
    int tid = threadIdx.x;
    if (tid == 0) carry_s = 0;
    __syncthreads();
    for (int base = 0; base < NN; base += 256) {
        int i = base + tid;
        int v = (i < NN) ? deg[i] : 0;
        buf[tid] = v;
        __syncthreads();
        #pragma unroll
        for (int off = 1; off < 256; off <<= 1) {
            int t = (tid >= off) ? buf[tid - off] : 0;
            __syncthreads();
            buf[tid] += t;
            __syncthreads();
        }
        if (i < NN) row_ptr[i] = carry_s + buf[tid] - v;  // exclusive
        int tot = buf[255];
        __syncthreads();
        if (tid == 0) carry_s += tot;
        __syncthreads();
    }
    if (tid == 0) row_ptr[NN] = carry_s;
}

__global__ __launch_bounds__(256) void build_kernel(const int* __restrict__ ei,
                                                    const float* __restrict__ ea,
                                                    const int* __restrict__ row_ptr,
                                                    int* __restrict__ cursor,
                                                    int* __restrict__ cols,
                                                    float* __restrict__ wv) {
    int e = blockIdx.x * 256 + threadIdx.x;
    if (e < EE) {
        int d = ei[e];           // dst
        int s = ei[EE + e];      // src
        int pos = atomicAdd(&cursor[d], 1);
        int idx = row_ptr[d] + pos;
        cols[idx] = s;
        wv[idx] = ea[e];
    }
}

// ---------------- Message passing, batch-fused ----------------
// One wave per node n. T arrays are node-major [N, B*F=512] fp32.
// Lane owns 8 floats: b = lane>>4, f = (lane&15)*8 -> per edge, wave gathers
// one contiguous 2KB row. Edge indices/weights loaded 64-wide coalesced and
// broadcast via v_readlane (SGPR-uniform -> scalar addressing).
// Tout[n] = coef * sum_e w[e]*Tin[col[e]] - Tsub[n].
// Strides parameterize x ([B,N,F]) vs T ([N,B,F]) layouts.
__global__ __launch_bounds__(256) void mp2_kernel(const float* __restrict__ Tin,
                                                  const float* __restrict__ Tsub,
                                                  float* __restrict__ Tout,
                                                  const int* __restrict__ row_ptr,
                                                  const int* __restrict__ cols,
                                                  const float* __restrict__ wv,
                                                  float coef,
                                                  int inRow, int inBatch,
                                                  int subRow, int subBatch) {
    int n = (blockIdx.x * 256 + threadIdx.x) >> 6;
    int lane = threadIdx.x & 63;
    int rs = __builtin_amdgcn_readfirstlane(row_ptr[n]);
    int re = __builtin_amdgcn_readfirstlane(row_ptr[n + 1]);
    int b = lane >> 4;
    int fi = (lane & 15) << 3;
    int loff = b * inBatch + fi;  // per-lane offset within a gathered row

    f32x4 a0 = {0.f, 0.f, 0.f, 0.f};
    f32x4 a1 = {0.f, 0.f, 0.f, 0.f};

    for (int e0 = rs; e0 < re; e0 += 64) {
        int cnt = re - e0;
        if (cnt > 64) cnt = 64;
        int cv = cols[e0 + lane];      // 64 edge indices, one coalesced load
        float wl = wv[e0 + lane];      // (cols/wv padded by 64 -> safe)
        #pragma unroll
        for (int j0 = 0; j0 < 64; j0 += 8) {
            if (j0 >= cnt) break;
            // issue up to 8 independent 2KB gathers before consuming
            f32x4 v[8][2];
            float w[8];
            #pragma unroll
            for (int j = 0; j < 8; ++j) {
                if (j0 + j < cnt) {
                    int c = __builtin_amdgcn_readlane(cv, j0 + j);
                    w[j] = __uint_as_float(__builtin_amdgcn_readlane(__float_as_uint(wl), j0 + j));
                    const float* p = Tin + (size_t)c * inRow + loff;
                    v[j][0] = *reinterpret_cast<const f32x4*>(p);
                    v[j][1] = *reinterpret_cast<const f32x4*>(p + 4);
                }
            }
            #pragma unroll
            for (int j = 0; j < 8; ++j) {
                if (j0 + j < cnt) {
                    a0 += w[j] * v[j][0];
                    a1 += w[j] * v[j][1];
                }
            }
        }
    }

    f32x4 r0 = coef * a0;
    f32x4 r1 = coef * a1;
    if (Tsub) {
        const float* sp = Tsub + (size_t)b * subBatch + (size_t)n * subRow + fi;
        r0 -= *reinterpret_cast<const f32x4*>(sp);
        r1 -= *reinterpret_cast<const f32x4*>(sp + 4);
    }
    float* op = Tout + (size_t)n * 512 + lane * 8;
    *reinterpret_cast<f32x4*>(op) = r0;
    *reinterpret_cast<f32x4*>(op + 4) = r1;
}

// ---------------- W^T prep: WT[pc][kk] bf16, pc = permuted phys col ----------------
// pc -> g=pc>>6 (wave), c64=pc&63, half=c64>>5 (0:Th0 1:Th1), o = g*32 + (c64&31)
__global__ __launch_bounds__(256) void prep_wt(const float* __restrict__ Th0,
                                               const float* __restrict__ Th1,
                                               bf16* __restrict__ WT) {
    int idx = blockIdx.x * 256 + threadIdx.x;  // 256*512 total
    int r = idx >> 9;
    int kk = idx & 511;
    int g = r >> 6, c64 = r & 63, half = c64 >> 5, o = g * 32 + (c64 & 31);
    int karr = kk >> 7, f = kk & 127;
    const float* src = half ? Th1 : Th0;
    WT[idx] = (bf16)src[(karr << 14) + (f << 7) + o];
}

// ---------------- MFMA combine ----------------
// Block: 128 nodes x 256 phys cols (128 outs x {Th0,Th1}), BK=64, K=512.
// 8 waves (2M x 4N), wave tile 64x64, acc[4][4] of 16x16 frags.
// LDS rows 128B: XOR-swizzle chunk^=(row&7) on write+read -> 2-way (free).
// A source: k=0 reads x [B,N,F]; k>0 reads Tk [N,B,F] (node-major).
__global__ __launch_bounds__(512) void combine_mfma(const float* __restrict__ x,
                                                    const float* __restrict__ T1,
                                                    const float* __restrict__ T2,
                                                    const float* __restrict__ T3,
                                                    const bf16* __restrict__ WT,
                                                    const float* __restrict__ bias,
                                                    const float* __restrict__ s_local,
                                                    float* __restrict__ out) {
    __shared__ bf16 As[128 * 64];  // 16 KB
    __shared__ bf16 Bs[256 * 64];  // 32 KB
    int b = blockIdx.y;
    int n0 = blockIdx.x * 128;
    int tid = threadIdx.x;
    int w = tid >> 6, lane = tid & 63;
    int wr = w >> 2, wc = w & 3;
    int l16 = lane & 15, lg = lane >> 4;

    f32x4 acc[4][4];
    #pragma unroll
    for (int mi = 0; mi < 4; ++mi)
        #pragma unroll
        for (int ni = 0; ni < 4; ++ni)
            acc[mi][ni] = (f32x4){0.f, 0.f, 0.f, 0.f};

    #pragma unroll
    for (int ks = 0; ks < 8; ++ks) {
        __syncthreads();  // previous compute done before overwrite
        const int karr = ks >> 1;
        const int f0 = (ks & 1) * 64;
        const float* __restrict__ Ak = (karr == 0) ? x : (karr == 1) ? T1 : (karr == 2) ? T2 : T3;
        // ---- stage A: 128 rows x 64 f, fp32 -> bf16, swizzled ----
        #pragma unroll
        for (int i = 0; i < 2; ++i) {
            int s = tid * 2 + i;
            int row = s >> 3, p = s & 7;
            int c = p ^ (row & 7);
            int gn = n0 + row;
            if (gn >= NN) gn = NN - 1;
            size_t off = (karr == 0) ? ((size_t)b * NN + gn) * FF
                                     : ((size_t)gn * BB + b) * FF;
            const float4* src = reinterpret_cast<const float4*>(Ak + off + f0 + c * 8);
            float4 v0 = src[0];
            float4 v1 = src[1];
            bf16x8 bv;
            bv[0] = (bf16)v0.x; bv[1] = (bf16)v0.y; bv[2] = (bf16)v0.z; bv[3] = (bf16)v0.w;
            bv[4] = (bf16)v1.x; bv[5] = (bf16)v1.y; bv[6] = (bf16)v1.z; bv[7] = (bf16)v1.w;
            *reinterpret_cast<bf16x8*>(&As[s * 8]) = bv;
        }
        // ---- stage B: 256 o-rows x 64 kk from WT (bf16 already), swizzled ----
        #pragma unroll
        for (int i = 0; i < 4; ++i) {
            int s = tid * 4 + i;
            int orow = s >> 3, p = s & 7;
            int c = p ^ (orow & 7);
            bf16x8 bv = *reinterpret_cast<const bf16x8*>(WT + orow * 512 + ks * 64 + c * 8);
            *reinterpret_cast<bf16x8*>(&Bs[s * 8]) = bv;
        }
        __syncthreads();
        // ---- fragments + MFMA ----
        #pragma unroll
        for (int ksub = 0; ksub < 2; ++ksub) {
            bf16x8 af[4], bfr[4];
            #pragma unroll
            for (int mi = 0; mi < 4; ++mi) {
                int row = wr * 64 + mi * 16 + l16;
                int cc = ksub * 4 + lg;
                int p = cc ^ (row & 7);
                af[mi] = *reinterpret_cast<const bf16x8*>(&As[row * 64 + p * 8]);
            }
            #pragma unroll
            for (int ni = 0; ni < 4; ++ni) {
                int orow = wc * 64 + ni * 16 + l16;
                int cc = ksub * 4 + lg;
                int p = cc ^ (orow & 7);
                bfr[ni] = *reinterpret_cast<const bf16x8*>(&Bs[orow * 64 + p * 8]);
            }
            #pragma unroll
            for (int mi = 0; mi < 4; ++mi)
                #pragma unroll
                for (int ni = 0; ni < 4; ++ni)
                    acc[mi][ni] = __builtin_amdgcn_mfma_f32_16x16x32_bf16(af[mi], bfr[ni], acc[mi][ni], 0, 0, 0);
        }
    }

    // ---- epilogue: out = acc0 + s*acc1 + bias (wave-local thanks to WT perm) ----
    #pragma unroll
    for (int ni = 0; ni < 2; ++ni) {
        int o = wc * 32 + ni * 16 + l16;
        float bs = bias[o];
        #pragma unroll
        for (int mi = 0; mi < 4; ++mi) {
            #pragma unroll
            for (int j = 0; j < 4; ++j) {
                int n = n0 + wr * 64 + mi * 16 + lg * 4 + j;
                if (n < NN) {
                    float sv = s_local[b * NN + n];
                    out[((size_t)b * NN + n) * FF + o] =
                        acc[mi][ni][j] + sv * acc[mi][ni + 2][j] + bs;
                }
            }
        }
    }
}

// ---------------- Launch ----------------

extern "C" void kernel_launch(void* const* d_in, const int* in_sizes, int n_in,
                              void* d_out, int out_size, void* d_ws, size_t ws_size,
                              hipStream_t stream) {
    const float* x       = (const float*)d_in[0];
    const int*   ei      = (const int*)d_in[1];
    const float* ea      = (const float*)d_in[2];
    const float* s_local = (const float*)d_in[3];
    const float* Th0     = (const float*)d_in[4];
    const float* Th1     = (const float*)d_in[5];
    const float* bias    = (const float*)d_in[6];
    float* out = (float*)d_out;

    // Workspace layout (~315 MB). T1..T3 are node-major [N, B*F].
    float* T1 = (float*)d_ws;
    float* T2 = T1 + BNF;
    float* T3 = T2 + BNF;
    bf16* WT = (bf16*)(T3 + BNF);  // 256*512 bf16 = 256 KB
    int* deg     = (int*)(WT + 256 * 512);
    int* cursor  = deg + NN;
    int* row_ptr = cursor + NN;
    int* cols    = row_ptr + (NN + 1);          // EE + 64 (padded for lane-wide loads)
    float* wv    = (float*)(cols + EE + 64);    // EE + 64

    hipMemsetAsync(deg, 0, 2 * NN * sizeof(int), stream);  // deg + cursor

    hist_kernel<<<(EE + 255) / 256, 256, 0, stream>>>(ei, deg);
    scan_kernel<<<1, 256, 0, stream>>>(deg, row_ptr);
    build_kernel<<<(EE + 255) / 256, 256, 0, stream>>>(ei, ea, row_ptr, cursor, cols, wv);
    prep_wt<<<512, 256, 0, stream>>>(Th0, Th1, WT);

    // Chebyshev: T1 = mp(x); T2 = 2*mp(T1) - x; T3 = 2*mp(T2) - T1
    const int mp_blocks = (NN * 64) / 256;  // one wave per node
    // x is [B,N,F]: row stride FF, batch stride NN*FF. T is [N,B,F]: row 512, batch FF.
    mp2_kernel<<<mp_blocks, 256, 0, stream>>>(x, nullptr, T1, row_ptr, cols, wv,
                                              1.0f, FF, NN * FF, 0, 0);
    mp2_kernel<<<mp_blocks, 256, 0, stream>>>(T1, x, T2, row_ptr, cols, wv,
                                              2.0f, BB * FF, FF, FF, NN * FF);
    mp2_kernel<<<mp_blocks, 256, 0, stream>>>(T2, T1, T3, row_ptr, cols, wv,
                                              2.0f, BB * FF, FF, BB * FF, FF);

    dim3 g((NN + 127) / 128, BB);
    combine_mfma<<<g, 512, 0, stream>>>(x, T1, T2, T3, WT, bias, s_local, out);
}

// Round 4
// 1009.880 us; speedup vs baseline: 2.1825x; 1.3566x over previous
//
#include <hip/hip_runtime.h>
#include <hip/hip_bf16.h>

// Problem constants: B=4, N=50000, F_IN=F_OUT=128, K=3, E=800000
#define BB 4
#define NN 50000
#define FF 128
#define EE 800000

typedef __bf16 bf16;
typedef __attribute__((ext_vector_type(8))) __bf16 bf16x8;
typedef __attribute__((ext_vector_type(4))) float f32x4;

__device__ inline void b2f(bf16x8 v, f32x4& lo, f32x4& hi) {
    #pragma unroll
    for (int i = 0; i < 4; ++i) lo[i] = (float)v[i];
    #pragma unroll
    for (int i = 0; i < 4; ++i) hi[i] = (float)v[i + 4];
}

// ---------------- CSR build (bucket edges by dst) ----------------

__global__ __launch_bounds__(256) void hist_kernel(const int* __restrict__ ei,
                                                   int* __restrict__ deg) {
    int e = blockIdx.x * 256 + threadIdx.x;
    if (e < EE) atomicAdd(&deg[ei[e]], 1);  // ei[0][e] = dst
}

__global__ __launch_bounds__(256) void scan_kernel(const int* __restrict__ deg,
                                                   int* __restrict__ row_ptr) {
    __shared__ int buf[256];
    __shared__ int carry_s;
    int tid = threadIdx.x;
    if (tid == 0) carry_s = 0;
    __syncthreads();
    for (int base = 0; base < NN; base += 256) {
        int i = base + tid;
        int v = (i < NN) ? deg[i] : 0;
        buf[tid] = v;
        __syncthreads();
        #pragma unroll
        for (int off = 1; off < 256; off <<= 1) {
            int t = (tid >= off) ? buf[tid - off] : 0;
            __syncthreads();
            buf[tid] += t;
            __syncthreads();
        }
        if (i < NN) row_ptr[i] = carry_s + buf[tid] - v;  // exclusive
        int tot = buf[255];
        __syncthreads();
        if (tid == 0) carry_s += tot;
        __syncthreads();
    }
    if (tid == 0) row_ptr[NN] = carry_s;
}

__global__ __launch_bounds__(256) void build_kernel(const int* __restrict__ ei,
                                                    const float* __restrict__ ea,
                                                    const int* __restrict__ row_ptr,
                                                    int* __restrict__ cursor,
                                                    int* __restrict__ cols,
                                                    float* __restrict__ wv) {
    int e = blockIdx.x * 256 + threadIdx.x;
    if (e < EE) {
        int d = ei[e];           // dst
        int s = ei[EE + e];      // src
        int pos = atomicAdd(&cursor[d], 1);
        int idx = row_ptr[d] + pos;
        cols[idx] = s;
        wv[idx] = ea[e];
    }
}

// ---------------- x -> node-major bf16 copy: Xb[n][b*128+f] ----------------
__global__ __launch_bounds__(256) void xcast_kernel(const float* __restrict__ x,
                                                    bf16* __restrict__ Xb) {
    int gid = blockIdx.x * 256 + threadIdx.x;  // NN*64 threads
    int n = gid >> 6;
    int lane = gid & 63;
    int b = lane >> 4;
    int f = (lane & 15) << 3;
    const float* p = x + ((size_t)b * NN + n) * FF + f;
    f32x4 v0 = *reinterpret_cast<const f32x4*>(p);
    f32x4 v1 = *reinterpret_cast<const f32x4*>(p + 4);
    bf16x8 o;
    #pragma unroll
    for (int i = 0; i < 4; ++i) { o[i] = (bf16)v0[i]; o[i + 4] = (bf16)v1[i]; }
    *reinterpret_cast<bf16x8*>(Xb + (size_t)n * 512 + lane * 8) = o;
}

// ---------------- Message passing, batch-fused, bf16 storage ----------------
// One wave per node n. T arrays node-major [N, 512] bf16 (1KB rows).
// Lane owns 8 elems (16B). Per edge: one contiguous 1KB wave-gather.
// Edge indices/weights loaded 64-wide coalesced, broadcast via readlane.
// Tout[n] = coef * sum_e w[e]*Tin[col[e]] - Tsub[n]. Accum fp32, store bf16.
__global__ __launch_bounds__(256) void mpb_kernel(const bf16* __restrict__ Tin,
                                                  const bf16* __restrict__ Tsub,
                                                  bf16* __restrict__ Tout,
                                                  const int* __restrict__ row_ptr,
                                                  const int* __restrict__ cols,
                                                  const float* __restrict__ wv,
                                                  float coef) {
    int n = (blockIdx.x * 256 + threadIdx.x) >> 6;
    int lane = threadIdx.x & 63;
    int rs = __builtin_amdgcn_readfirstlane(row_ptr[n]);
    int re = __builtin_amdgcn_readfirstlane(row_ptr[n + 1]);
    const bf16* __restrict__ base = Tin + lane * 8;

    f32x4 a0 = {0.f, 0.f, 0.f, 0.f};
    f32x4 a1 = {0.f, 0.f, 0.f, 0.f};

    for (int e0 = rs; e0 < re; e0 += 64) {
        int cnt = re - e0;
        if (cnt > 64) cnt = 64;
        int cv = cols[e0 + lane];      // 64 edge indices, one coalesced load
        float wl = wv[e0 + lane];      // (cols/wv padded by 64 -> safe)
        #pragma unroll
        for (int j0 = 0; j0 < 64; j0 += 8) {
            if (j0 >= cnt) break;
            // issue up to 8 independent 1KB gathers before consuming
            bf16x8 v[8];
            float w[8];
            #pragma unroll
            for (int j = 0; j < 8; ++j) {
                if (j0 + j < cnt) {
                    int c = __builtin_amdgcn_readlane(cv, j0 + j);
                    w[j] = __uint_as_float(__builtin_amdgcn_readlane(__float_as_uint(wl), j0 + j));
                    v[j] = *reinterpret_cast<const bf16x8*>(base + (size_t)c * 512);
                }
            }
            #pragma unroll
            for (int j = 0; j < 8; ++j) {
                if (j0 + j < cnt) {
                    f32x4 lo, hi;
                    b2f(v[j], lo, hi);
                    a0 += w[j] * lo;
                    a1 += w[j] * hi;
                }
            }
        }
    }

    f32x4 r0 = coef * a0;
    f32x4 r1 = coef * a1;
    if (Tsub) {
        bf16x8 s = *reinterpret_cast<const bf16x8*>(Tsub + (size_t)n * 512 + lane * 8);
        f32x4 slo, shi;
        b2f(s, slo, shi);
        r0 -= slo;
        r1 -= shi;
    }
    bf16x8 o;
    #pragma unroll
    for (int i = 0; i < 4; ++i) { o[i] = (bf16)r0[i]; o[i + 4] = (bf16)r1[i]; }
    *reinterpret_cast<bf16x8*>(Tout + (size_t)n * 512 + lane * 8) = o;
}

// ---------------- W^T prep: WT[pc][kk] bf16, pc = permuted phys col ----------------
// pc -> g=pc>>6 (wave), c64=pc&63, half=c64>>5 (0:Th0 1:Th1), o = g*32 + (c64&31)
__global__ __launch_bounds__(256) void prep_wt(const float* __restrict__ Th0,
                                               const float* __restrict__ Th1,
                                               bf16* __restrict__ WT) {
    int idx = blockIdx.x * 256 + threadIdx.x;  // 256*512 total
    int r = idx >> 9;
    int kk = idx & 511;
    int g = r >> 6, c64 = r & 63, half = c64 >> 5, o = g * 32 + (c64 & 31);
    int karr = kk >> 7, f = kk & 127;
    const float* src = half ? Th1 : Th0;
    WT[idx] = (bf16)src[(karr << 14) + (f << 7) + o];
}

// ---------------- MFMA combine ----------------
// Block: 128 nodes x 256 phys cols (128 outs x {Th0,Th1}), BK=64, K=512.
// 8 waves (2M x 4N), wave tile 64x64, acc[4][4] of 16x16 frags.
// LDS rows 128B: XOR-swizzle chunk^=(row&7) on write+read -> 2-way (free).
// A source: k=0 reads x fp32 [B,N,F] (exact T0); k>0 reads Tk bf16 [N,512].
__global__ __launch_bounds__(512) void combine_mfma(const float* __restrict__ x,
                                                    const bf16* __restrict__ T1,
                                                    const bf16* __restrict__ T2,
                                                    const bf16* __restrict__ T3,
                                                    const bf16* __restrict__ WT,
                                                    const float* __restrict__ bias,
                                                    const float* __restrict__ s_local,
                                                    float* __restrict__ out) {
    __shared__ bf16 As[128 * 64];  // 16 KB
    __shared__ bf16 Bs[256 * 64];  // 32 KB
    int b = blockIdx.y;
    int n0 = blockIdx.x * 128;
    int tid = threadIdx.x;
    int w = tid >> 6, lane = tid & 63;
    int wr = w >> 2, wc = w & 3;
    int l16 = lane & 15, lg = lane >> 4;

    f32x4 acc[4][4];
    #pragma unroll
    for (int mi = 0; mi < 4; ++mi)
        #pragma unroll
        for (int ni = 0; ni < 4; ++ni)
            acc[mi][ni] = (f32x4){0.f, 0.f, 0.f, 0.f};

    #pragma unroll
    for (int ks = 0; ks < 8; ++ks) {
        __syncthreads();  // previous compute done before overwrite
        const int karr = ks >> 1;
        const int f0 = (ks & 1) * 64;
        // ---- stage A: 128 rows x 64 f, swizzled ----
        #pragma unroll
        for (int i = 0; i < 2; ++i) {
            int s = tid * 2 + i;
            int row = s >> 3, p = s & 7;
            int c = p ^ (row & 7);
            int gn = n0 + row;
            if (gn >= NN) gn = NN - 1;
            if (karr == 0) {
                const float4* src = reinterpret_cast<const float4*>(
                    x + ((size_t)b * NN + gn) * FF + f0 + c * 8);
                float4 v0 = src[0];
                float4 v1 = src[1];
                bf16x8 bv;
                bv[0] = (bf16)v0.x; bv[1] = (bf16)v0.y; bv[2] = (bf16)v0.z; bv[3] = (bf16)v0.w;
                bv[4] = (bf16)v1.x; bv[5] = (bf16)v1.y; bv[6] = (bf16)v1.z; bv[7] = (bf16)v1.w;
                *reinterpret_cast<bf16x8*>(&As[s * 8]) = bv;
            } else {
                const bf16* Tk = (karr == 1) ? T1 : (karr == 2) ? T2 : T3;
                bf16x8 bv = *reinterpret_cast<const bf16x8*>(
                    Tk + (size_t)gn * 512 + b * FF + f0 + c * 8);
                *reinterpret_cast<bf16x8*>(&As[s * 8]) = bv;
            }
        }
        // ---- stage B: 256 o-rows x 64 kk from WT (bf16), swizzled ----
        #pragma unroll
        for (int i = 0; i < 4; ++i) {
            int s = tid * 4 + i;
            int orow = s >> 3, p = s & 7;
            int c = p ^ (orow & 7);
            bf16x8 bv = *reinterpret_cast<const bf16x8*>(WT + orow * 512 + ks * 64 + c * 8);
            *reinterpret_cast<bf16x8*>(&Bs[s * 8]) = bv;
        }
        __syncthreads();
        // ---- fragments + MFMA ----
        #pragma unroll
        for (int ksub = 0; ksub < 2; ++ksub) {
            bf16x8 af[4], bfr[4];
            #pragma unroll
            for (int mi = 0; mi < 4; ++mi) {
                int row = wr * 64 + mi * 16 + l16;
                int cc = ksub * 4 + lg;
                int p = cc ^ (row & 7);
                af[mi] = *reinterpret_cast<const bf16x8*>(&As[row * 64 + p * 8]);
            }
            #pragma unroll
            for (int ni = 0; ni < 4; ++ni) {
                int orow = wc * 64 + ni * 16 + l16;
                int cc = ksub * 4 + lg;
                int p = cc ^ (orow & 7);
                bfr[ni] = *reinterpret_cast<const bf16x8*>(&Bs[orow * 64 + p * 8]);
            }
            #pragma unroll
            for (int mi = 0; mi < 4; ++mi)
                #pragma unroll
                for (int ni = 0; ni < 4; ++ni)
                    acc[mi][ni] = __builtin_amdgcn_mfma_f32_16x16x32_bf16(af[mi], bfr[ni], acc[mi][ni], 0, 0, 0);
        }
    }

    // ---- epilogue: out = acc0 + s*acc1 + bias (wave-local thanks to WT perm) ----
    #pragma unroll
    for (int ni = 0; ni < 2; ++ni) {
        int o = wc * 32 + ni * 16 + l16;
        float bs = bias[o];
        #pragma unroll
        for (int mi = 0; mi < 4; ++mi) {
            #pragma unroll
            for (int j = 0; j < 4; ++j) {
                int n = n0 + wr * 64 + mi * 16 + lg * 4 + j;
                if (n < NN) {
                    float sv = s_local[b * NN + n];
                    out[((size_t)b * NN + n) * FF + o] =
                        acc[mi][ni][j] + sv * acc[mi][ni + 2][j] + bs;
                }
            }
        }
    }
}

// ---------------- Launch ----------------

extern "C" void kernel_launch(void* const* d_in, const int* in_sizes, int n_in,
                              void* d_out, int out_size, void* d_ws, size_t ws_size,
                              hipStream_t stream) {
    const float* x       = (const float*)d_in[0];
    const int*   ei      = (const int*)d_in[1];
    const float* ea      = (const float*)d_in[2];
    const float* s_local = (const float*)d_in[3];
    const float* Th0     = (const float*)d_in[4];
    const float* Th1     = (const float*)d_in[5];
    const float* bias    = (const float*)d_in[6];
    float* out = (float*)d_out;

    // Workspace: Xb,T1..T3 bf16 [N,512] (51.2 MB each) + WT + CSR (~210 MB)
    const size_t TSZ = (size_t)NN * 512;  // elements per bf16 T array
    bf16* Xb = (bf16*)d_ws;
    bf16* T1 = Xb + TSZ;
    bf16* T2 = T1 + TSZ;
    bf16* T3 = T2 + TSZ;
    bf16* WT = T3 + TSZ;  // 256*512 bf16 = 256 KB
    int* deg     = (int*)(WT + 256 * 512);
    int* cursor  = deg + NN;
    int* row_ptr = cursor + NN;
    int* cols    = row_ptr + (NN + 1);          // EE + 64 (padded)
    float* wv    = (float*)(cols + EE + 64);    // EE + 64

    hipMemsetAsync(deg, 0, 2 * NN * sizeof(int), stream);  // deg + cursor

    hist_kernel<<<(EE + 255) / 256, 256, 0, stream>>>(ei, deg);
    scan_kernel<<<1, 256, 0, stream>>>(deg, row_ptr);
    build_kernel<<<(EE + 255) / 256, 256, 0, stream>>>(ei, ea, row_ptr, cursor, cols, wv);
    prep_wt<<<512, 256, 0, stream>>>(Th0, Th1, WT);
    xcast_kernel<<<(NN * 64) / 256, 256, 0, stream>>>(x, Xb);

    // Chebyshev: T1 = mp(Xb); T2 = 2*mp(T1) - Xb; T3 = 2*mp(T2) - T1
    const int mp_blocks = (NN * 64) / 256;  // one wave per node
    mpb_kernel<<<mp_blocks, 256, 0, stream>>>(Xb, nullptr, T1, row_ptr, cols, wv, 1.0f);
    mpb_kernel<<<mp_blocks, 256, 0, stream>>>(T1, Xb, T2, row_ptr, cols, wv, 2.0f);
    mpb_kernel<<<mp_blocks, 256, 0, stream>>>(T2, T1, T3, row_ptr, cols, wv, 2.0f);

    dim3 g((NN + 127) / 128, BB);
    combine_mfma<<<g, 512, 0, stream>>>(x, T1, T2, T3, WT, bias, s_local, out);
}